// Round 1
// baseline (415.519 us; speedup 1.0000x reference)
//
#include <hip/hip_runtime.h>
#include <math.h>

#define DIM   128
#define SLICE (DIM*DIM)       // 16384
#define VOL   (DIM*DIM*DIM)   // 2097152
#define NB    2
#define NK    4
#define NVOL  (NB*NK)         // 8

// Gaussian taps exp(-x^2/(2*5^2)), x=-4..4 (unnormalized, matches reference)
__constant__ float c_g[9] = {
    0.72614904f, 0.83527021f, 0.92311635f, 0.98019867f, 1.0f,
    0.98019867f, 0.92311635f, 0.83527021f, 0.72614904f
};

// ws layout (floats): [0..7] sumP per vol, [8..15] sumIP per vol,
//                     [16..19] num per class, [20..23] den per class
// A buffer (wh-blurred labels) starts at byte offset 256.

// K1: one block per (vol, d) slice. Computes sumP/sumIP partials and the
// w-blur (from global, L1-served overlaps) then h-blur (via LDS) of labels.
__global__ __launch_bounds__(256) void k_slice(
    const float* __restrict__ labels, const float* __restrict__ inputs,
    float* __restrict__ A, float* __restrict__ red)
{
    __shared__ float sTmp[SLICE];   // 64 KiB: w-blurred slice
    const int sliceId = blockIdx.x;         // vol*128 + d
    const int vol = sliceId >> 7;
    const int d   = sliceId & 127;
    const int b   = vol >> 2;
    const float* __restrict__ src  = labels + (size_t)vol*VOL + (size_t)d*SLICE;
    const float* __restrict__ isrc = inputs + (size_t)b  *VOL + (size_t)d*SLICE;
    float* __restrict__ dst = A + (size_t)vol*VOL + (size_t)d*SLICE;
    const int t = threadIdx.x;

    float sp = 0.f, sip = 0.f;
    for (int i = t; i < SLICE; i += 256) {
        const int w = i & 127;
        const float c  = src[i];
        const float iv = isrc[i];
        sp  += c;
        sip += c * iv;
        float acc = c_g[4] * c;
        #pragma unroll
        for (int dt = 1; dt <= 4; ++dt) {
            if (w + dt < 128) acc += c_g[4+dt] * src[i+dt];
            if (w - dt >= 0)  acc += c_g[4-dt] * src[i-dt];
        }
        sTmp[i] = acc;
    }
    // wave-reduce the slice sums, one atomic per wave
    #pragma unroll
    for (int o = 32; o; o >>= 1) { sp += __shfl_down(sp, o); sip += __shfl_down(sip, o); }
    if ((t & 63) == 0) { atomicAdd(&red[vol], sp); atomicAdd(&red[8+vol], sip); }

    __syncthreads();
    for (int i = t; i < SLICE; i += 256) {
        const int h = i >> 7;
        float acc = c_g[4] * sTmp[i];
        #pragma unroll
        for (int dt = 1; dt <= 4; ++dt) {
            if (h + dt < 128) acc += c_g[4+dt] * sTmp[i + 128*dt];
            if (h - dt >= 0)  acc += c_g[4-dt] * sTmp[i - 128*dt];
        }
        dst[i] = acc;
    }
}

// K2: d-blur of A via a 9-register ring (each A element loaded once per chunk),
// fused with weights computation and the num/den reductions.
__global__ __launch_bounds__(256) void k_dblur_reduce(
    const float* __restrict__ A, const float* __restrict__ labels,
    const float* __restrict__ inputs, const float* __restrict__ red,
    float* __restrict__ nd)
{
    const int blk   = blockIdx.x;      // vol(8) x chunk(2) x hpair(64)
    const int hp    = blk & 63;
    const int chunk = (blk >> 6) & 1;
    const int vol   = blk >> 7;
    const int b = vol >> 2, k = vol & 3;
    const int h = hp*2 + (threadIdx.x >> 7);
    const int w = threadIdx.x & 127;
    const size_t sbase = (size_t)h*128 + w;
    const float* __restrict__ Av = A      + (size_t)vol*VOL + sbase;
    const float* __restrict__ Pv = labels + (size_t)vol*VOL + sbase;
    const float* __restrict__ Iv = inputs + (size_t)b  *VOL + sbase;

    // class mean: sumIP / (sumP + 1e-5*V)
    const float mean = red[8+vol] / (red[vol] + 20.97152f);

    const int d0 = chunk * 64;
    float ring[9];
    #pragma unroll
    for (int i = 0; i < 9; ++i) ring[i] = 0.f;
    float numAcc = 0.f, denAcc = 0.f;

    for (int s = d0 - 4; s < d0 + 68; ++s) {
        #pragma unroll
        for (int i = 0; i < 8; ++i) ring[i] = ring[i+1];
        ring[8] = (s >= 0 && s < 128) ? Av[(size_t)s*SLICE] : 0.f;
        const int dc = s - 4;
        if (dc >= d0 && dc < d0 + 64) {
            float B = 0.f;
            #pragma unroll
            for (int i = 0; i < 9; ++i) B += c_g[i] * ring[i];
            const float p  = Pv[(size_t)dc*SLICE];
            const float iv = Iv[(size_t)dc*SLICE];
            float df = iv - mean; df = df * df;       // (I-mean)^2
            const float wgt = expf(-df * df);          // exp(-diff^2)
            const float bw = B * wgt;
            numAcc += bw * p;
            denAcc += bw;
        }
    }

    #pragma unroll
    for (int o = 32; o; o >>= 1) { numAcc += __shfl_down(numAcc, o); denAcc += __shfl_down(denAcc, o); }
    __shared__ float sN[4], sD[4];
    const int wid = threadIdx.x >> 6;
    if ((threadIdx.x & 63) == 0) { sN[wid] = numAcc; sD[wid] = denAcc; }
    __syncthreads();
    if (threadIdx.x == 0) {
        atomicAdd(&nd[k],     sN[0]+sN[1]+sN[2]+sN[3]);
        atomicAdd(&nd[4+k],   sD[0]+sD[1]+sD[2]+sD[3]);
    }
}

__global__ void k_final(const float* __restrict__ red, float* __restrict__ out)
{
    float loss = 0.f;
    #pragma unroll
    for (int k = 0; k < 4; ++k) loss += fabsf(red[16+k] / (red[20+k] + 1e-6f));
    out[0] = (float)NK - loss;
}

extern "C" void kernel_launch(void* const* d_in, const int* in_sizes, int n_in,
                              void* d_out, int out_size, void* d_ws, size_t ws_size,
                              hipStream_t stream)
{
    const float* labels = (const float*)d_in[0];   // (2,4,128,128,128)
    const float* inputs = (const float*)d_in[1];   // (2,1,128,128,128)
    float* out = (float*)d_out;
    float* red = (float*)d_ws;
    float* A   = (float*)((char*)d_ws + 256);      // 64 MiB wh-blurred labels

    hipMemsetAsync(red, 0, 24*sizeof(float), stream);
    k_slice<<<NVOL*DIM, 256, 0, stream>>>(labels, inputs, A, red);
    k_dblur_reduce<<<NVOL*2*64, 256, 0, stream>>>(A, labels, inputs, red, red + 16);
    k_final<<<1, 1, 0, stream>>>(red, out);
}

// Round 2
// 253.849 us; speedup vs baseline: 1.6369x; 1.6369x over previous
//
#include <hip/hip_runtime.h>
#include <math.h>

#define DIM   128
#define SLICE (DIM*DIM)       // 16384
#define VOL   (DIM*DIM*DIM)   // 2097152
#define NB    2
#define NK    4
#define NVOL  (NB*NK)         // 8

// Gaussian taps exp(-x^2/(2*5^2)), x=-4..4 (unnormalized, matches reference)
__constant__ float c_g[9] = {
    0.72614904f, 0.83527021f, 0.92311635f, 0.98019867f, 1.0f,
    0.98019867f, 0.92311635f, 0.83527021f, 0.72614904f
};

// ws layout (floats): [0..7] sumP per vol, [8..15] sumIP per vol,
//                     [16..19] num per class, [20..23] den per class
// A buffer (wh-blurred labels) starts at byte offset 256.

// K1: one block per (vol, d, h-chunk of 32 rows). Single 20 KiB LDS buffer:
// float4 load -> w-blur into regs -> write back -> h-blur (float4) -> store.
__global__ __launch_bounds__(256) void k_slice(
    const float* __restrict__ labels, const float* __restrict__ inputs,
    float* __restrict__ A, float* __restrict__ red)
{
    __shared__ float sT[40*128];     // 20 KiB -> up to 8 blocks/CU (LDS-wise)
    __shared__ float sRed[8];
    const int hc  = blockIdx.x & 3;
    const int d   = (blockIdx.x >> 2) & 127;
    const int vol = blockIdx.x >> 9;
    const int b   = vol >> 2;
    const int h0  = hc * 32;
    const float* __restrict__ src  = labels + (size_t)vol*VOL + (size_t)d*SLICE;
    const float* __restrict__ isrc = inputs + (size_t)b  *VOL + (size_t)d*SLICE;
    float* __restrict__ dst = A + (size_t)vol*VOL + (size_t)d*SLICE;
    const int t = threadIdx.x;

    // 1) load 40 rows (global h = h0-4 .. h0+35), zeros outside -> h-blur needs
    //    no bounds checks later.
    for (int i = t; i < 40*32; i += 256) {          // 5 float4 per thread
        const int r  = i >> 5;
        const int h  = h0 - 4 + r;
        float4 v = make_float4(0.f, 0.f, 0.f, 0.f);
        if (h >= 0 && h < 128) v = ((const float4*)(src + h*128))[i & 31];
        ((float4*)sT)[i] = v;
    }
    __syncthreads();

    // 2a) slice sums over owned rows (labels from LDS, inputs float4 global)
    float sp = 0.f, sip = 0.f;
    for (int i = t; i < 32*32; i += 256) {          // 4 float4 per thread
        const int r = i >> 5, wq = i & 31;
        const float4 c  = ((const float4*)sT)[(r+4)*32 + wq];
        const float4 iv = ((const float4*)(isrc + (h0+r)*128))[wq];
        sp  += c.x + c.y + c.z + c.w;
        sip += c.x*iv.x + c.y*iv.y + c.z*iv.z + c.w*iv.w;
    }
    #pragma unroll
    for (int o = 32; o; o >>= 1) { sp += __shfl_down(sp, o); sip += __shfl_down(sip, o); }
    if ((t & 63) == 0) { sRed[t >> 6] = sp; sRed[4 + (t >> 6)] = sip; }

    // 2b) w-blur of all 40 rows into registers (stride-1 LDS reads: conflict-free)
    float wb[20];
    #pragma unroll
    for (int j = 0; j < 20; ++j) {
        const int i = t + j*256;                    // covers 40*128 = 5120
        const int r = i >> 7, w = i & 127;
        float acc = sT[r*128 + w];                  // center tap = 1.0
        #pragma unroll
        for (int dt = 1; dt <= 4; ++dt) {
            const float a  = (w + dt < 128) ? sT[r*128 + w + dt] : 0.f;
            const float b2 = (w - dt >=  0) ? sT[r*128 + w - dt] : 0.f;
            acc += c_g[4+dt] * (a + b2);            // symmetric taps
        }
        wb[j] = acc;
    }
    __syncthreads();
    #pragma unroll
    for (int j = 0; j < 20; ++j) sT[t + j*256] = wb[j];
    __syncthreads();

    if (t == 0) {
        atomicAdd(&red[vol],   sRed[0]+sRed[1]+sRed[2]+sRed[3]);
        atomicAdd(&red[8+vol], sRed[4]+sRed[5]+sRed[6]+sRed[7]);
    }

    // 3) h-blur (float4 LDS reads, 16B lane stride) + float4 global store
    for (int i = t; i < 32*32; i += 256) {
        const int r = i >> 5, wq = i & 31;          // output row h0+r = tile row r+4
        const float4* sT4 = (const float4*)sT;
        float4 acc = sT4[(r+4)*32 + wq];
        #pragma unroll
        for (int dt = 1; dt <= 4; ++dt) {
            const float4 a  = sT4[(r+4+dt)*32 + wq];
            const float4 b2 = sT4[(r+4-dt)*32 + wq];
            const float g = c_g[4+dt];
            acc.x += g*(a.x+b2.x); acc.y += g*(a.y+b2.y);
            acc.z += g*(a.z+b2.z); acc.w += g*(a.w+b2.w);
        }
        ((float4*)(dst + (h0+r)*128))[wq] = acc;
    }
}

// K2: d-blur of A via a float4 9-register ring, fused with weights + reductions.
// Block covers 8 h-rows (256 threads x float4); d split into 4 chunks of 32.
__global__ __launch_bounds__(256) void k_dblur_reduce(
    const float* __restrict__ A, const float* __restrict__ labels,
    const float* __restrict__ inputs, const float* __restrict__ red,
    float* __restrict__ nd)
{
    const int dc  = blockIdx.x & 3;
    const int hcc = (blockIdx.x >> 2) & 15;
    const int vol = blockIdx.x >> 6;
    const int b = vol >> 2, k = vol & 3;
    const int row = threadIdx.x >> 5;               // 0..7
    const int wq  = threadIdx.x & 31;
    const int h   = hcc*8 + row;
    const size_t base = (size_t)vol*VOL + (size_t)h*128 + wq*4;
    const float4* __restrict__ A4 = (const float4*)(A + base);
    const float4* __restrict__ P4 = (const float4*)(labels + base);
    const float4* __restrict__ I4 = (const float4*)(inputs + (size_t)b*VOL + (size_t)h*128 + wq*4);

    // class mean = sumIP / (sumP + 1e-5*V)
    const float mean = red[8+vol] / (red[vol] + 20.97152f);
    const int d0 = dc * 32;

    float4 ring[9];
    #pragma unroll
    for (int i = 0; i < 9; ++i) ring[i] = make_float4(0.f,0.f,0.f,0.f);
    float numAcc = 0.f, denAcc = 0.f;

    for (int s = d0 - 4; s < d0 + 36; ++s) {
        #pragma unroll
        for (int i = 0; i < 8; ++i) ring[i] = ring[i+1];
        float4 v = make_float4(0.f,0.f,0.f,0.f);
        if (s >= 0 && s < 128) v = A4[(size_t)s * (SLICE/4)];
        ring[8] = v;
        const int dcur = s - 4;
        if (dcur >= d0) {
            float4 B = ring[4];                     // center tap = 1.0
            #pragma unroll
            for (int dt = 1; dt <= 4; ++dt) {
                const float g = c_g[4+dt];
                B.x += g*(ring[4+dt].x + ring[4-dt].x);
                B.y += g*(ring[4+dt].y + ring[4-dt].y);
                B.z += g*(ring[4+dt].z + ring[4-dt].z);
                B.w += g*(ring[4+dt].w + ring[4-dt].w);
            }
            const float4 p  = P4[(size_t)dcur * (SLICE/4)];
            const float4 iv = I4[(size_t)dcur * (SLICE/4)];
            {
                float df = iv.x - mean; df *= df;
                const float bw = B.x * __expf(-df*df);
                numAcc += bw * p.x; denAcc += bw;
            }
            {
                float df = iv.y - mean; df *= df;
                const float bw = B.y * __expf(-df*df);
                numAcc += bw * p.y; denAcc += bw;
            }
            {
                float df = iv.z - mean; df *= df;
                const float bw = B.z * __expf(-df*df);
                numAcc += bw * p.z; denAcc += bw;
            }
            {
                float df = iv.w - mean; df *= df;
                const float bw = B.w * __expf(-df*df);
                numAcc += bw * p.w; denAcc += bw;
            }
        }
    }

    #pragma unroll
    for (int o = 32; o; o >>= 1) { numAcc += __shfl_down(numAcc, o); denAcc += __shfl_down(denAcc, o); }
    __shared__ float sN[4], sD[4];
    const int wid = threadIdx.x >> 6;
    if ((threadIdx.x & 63) == 0) { sN[wid] = numAcc; sD[wid] = denAcc; }
    __syncthreads();
    if (threadIdx.x == 0) {
        atomicAdd(&nd[k],   sN[0]+sN[1]+sN[2]+sN[3]);
        atomicAdd(&nd[4+k], sD[0]+sD[1]+sD[2]+sD[3]);
    }
}

__global__ void k_final(const float* __restrict__ red, float* __restrict__ out)
{
    float loss = 0.f;
    #pragma unroll
    for (int k = 0; k < 4; ++k) loss += fabsf(red[16+k] / (red[20+k] + 1e-6f));
    out[0] = (float)NK - loss;
}

extern "C" void kernel_launch(void* const* d_in, const int* in_sizes, int n_in,
                              void* d_out, int out_size, void* d_ws, size_t ws_size,
                              hipStream_t stream)
{
    const float* labels = (const float*)d_in[0];   // (2,4,128,128,128)
    const float* inputs = (const float*)d_in[1];   // (2,1,128,128,128)
    float* out = (float*)d_out;
    float* red = (float*)d_ws;
    float* A   = (float*)((char*)d_ws + 256);      // 64 MiB wh-blurred labels

    hipMemsetAsync(red, 0, 24*sizeof(float), stream);
    k_slice<<<NVOL*DIM*4, 256, 0, stream>>>(labels, inputs, A, red);
    k_dblur_reduce<<<NVOL*16*4, 256, 0, stream>>>(A, labels, inputs, red, red + 16);
    k_final<<<1, 1, 0, stream>>>(red, out);
}

// Round 3
// 245.496 us; speedup vs baseline: 1.6926x; 1.0340x over previous
//
#include <hip/hip_runtime.h>
#include <math.h>

#define DIM   128
#define SLICE (DIM*DIM)       // 16384
#define VOL   (DIM*DIM*DIM)   // 2097152
#define NB    2
#define NK    4
#define NVOL  (NB*NK)         // 8

// Gaussian taps exp(-x^2/(2*5^2)), x=-4..4 (unnormalized, matches reference)
__constant__ float c_g[9] = {
    0.72614904f, 0.83527021f, 0.92311635f, 0.98019867f, 1.0f,
    0.98019867f, 0.92311635f, 0.83527021f, 0.72614904f
};

// LDS tile: 40 rows x 34 float4 (cols 0 and 33 are zero pads, data in 1..32)
#define RSTR 34   // row stride in float4

// K1: one block per (vol, d, h-chunk of 32 rows).
// float4 everywhere: load -> w-blur (3 b128 reads / 4 outputs) -> writeback ->
// h-blur (12-row register ring) -> float4 store.
__global__ __launch_bounds__(256) void k_slice(
    const float* __restrict__ labels, const float* __restrict__ inputs,
    float* __restrict__ A, float* __restrict__ red)
{
    __shared__ float4 sT4[40*RSTR];   // 21760 B
    __shared__ float sRed[8];
    const int hc  = blockIdx.x & 3;
    const int d   = (blockIdx.x >> 2) & 127;
    const int vol = blockIdx.x >> 9;
    const int b   = vol >> 2;
    const int h0  = hc * 32;
    const float* __restrict__ src  = labels + (size_t)vol*VOL + (size_t)d*SLICE;
    const float* __restrict__ isrc = inputs + (size_t)b  *VOL + (size_t)d*SLICE;
    float* __restrict__ dst = A + (size_t)vol*VOL + (size_t)d*SLICE;
    const int t = threadIdx.x;
    const float g1 = c_g[5], g2 = c_g[6], g3 = c_g[7], g4 = c_g[8];

    // 1) zero pads + load 40 rows (global h = h0-4 .. h0+35, zeros outside)
    if (t < 80) sT4[(t >> 1)*RSTR + ((t & 1) ? 33 : 0)] = make_float4(0.f,0.f,0.f,0.f);
    for (int i = t; i < 40*32; i += 256) {          // 5 float4 per thread
        const int r = i >> 5, c = i & 31;
        const int h = h0 - 4 + r;
        float4 v = make_float4(0.f,0.f,0.f,0.f);
        if (h >= 0 && h < 128) v = ((const float4*)(src + h*128))[c];
        sT4[r*RSTR + 1 + c] = v;
    }
    __syncthreads();

    // 2a) slice sums over owned rows (labels from LDS, inputs float4 global)
    float sp = 0.f, sip = 0.f;
    #pragma unroll
    for (int j = 0; j < 4; ++j) {
        const int i = t + j*256;                    // 32*32 float4
        const int r = i >> 5, c = i & 31;
        const float4 cv = sT4[(r+4)*RSTR + 1 + c];
        const float4 iv = ((const float4*)(isrc + (h0+r)*128))[c];
        sp  += cv.x + cv.y + cv.z + cv.w;
        sip += cv.x*iv.x + cv.y*iv.y + cv.z*iv.z + cv.w*iv.w;
    }
    #pragma unroll
    for (int o = 32; o; o >>= 1) { sp += __shfl_down(sp, o); sip += __shfl_down(sip, o); }
    if ((t & 63) == 0) { sRed[t >> 6] = sp; sRed[4 + (t >> 6)] = sip; }

    // 2b) w-blur: 3 float4 reads -> 4 outputs, for all 40 rows
    float4 wb[5];
    #pragma unroll
    for (int j = 0; j < 5; ++j) {
        const int i = t + j*256;                    // 40*32 float4
        const int r = i >> 5, c = i & 31;
        const float4 pv = sT4[r*RSTR + c];          // w-4..w-1
        const float4 cv = sT4[r*RSTR + c + 1];      // w0..w3
        const float4 nx = sT4[r*RSTR + c + 2];      // w4..w7
        float4 o;
        o.x = cv.x + g1*(pv.w + cv.y) + g2*(pv.z + cv.z) + g3*(pv.y + cv.w) + g4*(pv.x + nx.x);
        o.y = cv.y + g1*(cv.x + cv.z) + g2*(pv.w + cv.w) + g3*(pv.z + nx.x) + g4*(pv.y + nx.y);
        o.z = cv.z + g1*(cv.y + cv.w) + g2*(cv.x + nx.x) + g3*(pv.w + nx.y) + g4*(pv.z + nx.z);
        o.w = cv.w + g1*(cv.z + nx.x) + g2*(cv.y + nx.y) + g3*(cv.x + nx.z) + g4*(pv.w + nx.w);
        wb[j] = o;
    }
    __syncthreads();
    #pragma unroll
    for (int j = 0; j < 5; ++j) {
        const int i = t + j*256;
        const int r = i >> 5, c = i & 31;
        sT4[r*RSTR + c + 1] = wb[j];
    }
    if (t == 0) {
        atomicAdd(&red[vol],   sRed[0]+sRed[1]+sRed[2]+sRed[3]);
        atomicAdd(&red[8+vol], sRed[4]+sRed[5]+sRed[6]+sRed[7]);
    }
    __syncthreads();

    // 3) h-blur: 12-row register ring -> 4 output rows per thread
    {
        const int c = t & 31;       // float4 column
        const int g = t >> 5;       // row group 0..7
        float4 r0[12];
        #pragma unroll
        for (int j = 0; j < 12; ++j) r0[j] = sT4[(g*4 + j)*RSTR + 1 + c];
        #pragma unroll
        for (int k = 0; k < 4; ++k) {
            float4 acc = r0[4+k];
            #pragma unroll
            for (int dt = 1; dt <= 4; ++dt) {
                const float g_ = c_g[4+dt];
                acc.x += g_*(r0[4+k-dt].x + r0[4+k+dt].x);
                acc.y += g_*(r0[4+k-dt].y + r0[4+k+dt].y);
                acc.z += g_*(r0[4+k-dt].z + r0[4+k+dt].z);
                acc.w += g_*(r0[4+k-dt].w + r0[4+k+dt].w);
            }
            ((float4*)(dst + (h0 + g*4 + k)*128))[c] = acc;
        }
    }
}

// K2: d-blur of A via a float4 9-register ring, fused with weights + reductions.
// Block: 8 h-rows x 128 w; d split into 8 chunks of 16 -> 1024 blocks.
__global__ __launch_bounds__(256) void k_dblur_reduce(
    const float* __restrict__ A, const float* __restrict__ labels,
    const float* __restrict__ inputs, const float* __restrict__ red,
    float* __restrict__ nd)
{
    const int dc  = blockIdx.x & 7;
    const int hcc = (blockIdx.x >> 3) & 15;
    const int vol = blockIdx.x >> 7;
    const int b = vol >> 2, k = vol & 3;
    const int row = threadIdx.x >> 5;               // 0..7
    const int wq  = threadIdx.x & 31;
    const int h   = hcc*8 + row;
    const size_t base = (size_t)vol*VOL + (size_t)h*128 + wq*4;
    const float4* __restrict__ A4 = (const float4*)(A + base);
    const float4* __restrict__ P4 = (const float4*)(labels + base);
    const float4* __restrict__ I4 = (const float4*)(inputs + (size_t)b*VOL + (size_t)h*128 + wq*4);

    // class mean = sumIP / (sumP + 1e-5*V)
    const float mean = red[8+vol] / (red[vol] + 20.97152f);
    const int d0 = dc * 16;

    float4 ring[9];
    #pragma unroll
    for (int i = 0; i < 9; ++i) ring[i] = make_float4(0.f,0.f,0.f,0.f);
    float numAcc = 0.f, denAcc = 0.f;

    #pragma unroll
    for (int it = 0; it < 24; ++it) {
        const int s = d0 - 4 + it;
        #pragma unroll
        for (int i = 0; i < 8; ++i) ring[i] = ring[i+1];
        float4 v = make_float4(0.f,0.f,0.f,0.f);
        if (s >= 0 && s < 128) v = A4[(size_t)s * (SLICE/4)];
        ring[8] = v;
        if (it >= 8) {
            const int dcur = s - 4;                 // d0 .. d0+15
            float4 B = ring[4];                     // center tap = 1.0
            #pragma unroll
            for (int dt = 1; dt <= 4; ++dt) {
                const float g = c_g[4+dt];
                B.x += g*(ring[4+dt].x + ring[4-dt].x);
                B.y += g*(ring[4+dt].y + ring[4-dt].y);
                B.z += g*(ring[4+dt].z + ring[4-dt].z);
                B.w += g*(ring[4+dt].w + ring[4-dt].w);
            }
            const float4 p  = P4[(size_t)dcur * (SLICE/4)];
            const float4 iv = I4[(size_t)dcur * (SLICE/4)];
            { float df = iv.x - mean; df *= df; const float bw = B.x * __expf(-df*df); numAcc += bw * p.x; denAcc += bw; }
            { float df = iv.y - mean; df *= df; const float bw = B.y * __expf(-df*df); numAcc += bw * p.y; denAcc += bw; }
            { float df = iv.z - mean; df *= df; const float bw = B.z * __expf(-df*df); numAcc += bw * p.z; denAcc += bw; }
            { float df = iv.w - mean; df *= df; const float bw = B.w * __expf(-df*df); numAcc += bw * p.w; denAcc += bw; }
        }
    }

    #pragma unroll
    for (int o = 32; o; o >>= 1) { numAcc += __shfl_down(numAcc, o); denAcc += __shfl_down(denAcc, o); }
    __shared__ float sN[4], sD[4];
    const int wid = threadIdx.x >> 6;
    if ((threadIdx.x & 63) == 0) { sN[wid] = numAcc; sD[wid] = denAcc; }
    __syncthreads();
    if (threadIdx.x == 0) {
        atomicAdd(&nd[k],   sN[0]+sN[1]+sN[2]+sN[3]);
        atomicAdd(&nd[4+k], sD[0]+sD[1]+sD[2]+sD[3]);
    }
}

__global__ void k_final(const float* __restrict__ red, float* __restrict__ out)
{
    float loss = 0.f;
    #pragma unroll
    for (int k = 0; k < 4; ++k) loss += fabsf(red[16+k] / (red[20+k] + 1e-6f));
    out[0] = (float)NK - loss;
}

extern "C" void kernel_launch(void* const* d_in, const int* in_sizes, int n_in,
                              void* d_out, int out_size, void* d_ws, size_t ws_size,
                              hipStream_t stream)
{
    const float* labels = (const float*)d_in[0];   // (2,4,128,128,128)
    const float* inputs = (const float*)d_in[1];   // (2,1,128,128,128)
    float* out = (float*)d_out;
    float* red = (float*)d_ws;
    float* A   = (float*)((char*)d_ws + 256);      // 64 MiB wh-blurred labels

    hipMemsetAsync(red, 0, 24*sizeof(float), stream);
    k_slice<<<NVOL*DIM*4, 256, 0, stream>>>(labels, inputs, A, red);
    k_dblur_reduce<<<NVOL*16*8, 256, 0, stream>>>(A, labels, inputs, red, red + 16);
    k_final<<<1, 1, 0, stream>>>(red, out);
}